// Round 1
// baseline (666.391 us; speedup 1.0000x reference)
//
#include <hip/hip_runtime.h>

constexpr int NB = 4;     // batch
constexpr int NS = 256;   // N nodes
constexpr int NT = 64;    // T
constexpr int ND = 128;   // D
constexpr int NH = 128;   // DH
constexpr int NR = 32;    // DR
constexpr int WFR = 3 * ND + NR;              // 416
constexpr float SCALE = 0.08838834764831845f; // 1/sqrt(128)

// ---------------- kernel A: Ej[b,j,e] = (sum_t dH[b,j,t,:]) . W4[e,:]
__global__ __launch_bounds__(128) void kA(const float* __restrict__ dH,
                                          const float* __restrict__ Wf,
                                          float* __restrict__ Ej) {
  __shared__ float ds[ND];
  const int bj = blockIdx.x;
  const int d = threadIdx.x;
  const float* p = dH + (size_t)bj * NT * ND + d;
  float s = 0.f;
  #pragma unroll 8
  for (int t = 0; t < NT; ++t) s += p[t * ND];
  ds[d] = s;
  __syncthreads();
  const float* w4 = Wf + (size_t)d * WFR + 2 * ND + NR;
  float acc = 0.f;
  #pragma unroll 8
  for (int dd = 0; dd < ND; ++dd) acc += ds[dd] * w4[dd];
  Ej[(size_t)bj * ND + d] = acc;
}

// ---------------- kernel B: q,k,Apb(=A+bf),BE(=Bj+Ej) for one (b,n) row block
__global__ __launch_bounds__(256) void kB(const float* __restrict__ H,
    const float* __restrict__ Wq, const float* __restrict__ bq,
    const float* __restrict__ Wk, const float* __restrict__ bk,
    const float* __restrict__ Wf, const float* __restrict__ bf,
    const float* __restrict__ Ej,
    float* __restrict__ qo, float* __restrict__ ko,
    float* __restrict__ Ao, float* __restrict__ BEo) {
  __shared__ __align__(16) float Hs[NT * 132];
  __shared__ __align__(16) float Ws[128 * 132];
  const int bn = blockIdx.x;
  const int tid = threadIdx.x;
  const float* hsrc = H + (size_t)bn * NT * ND;
  #pragma unroll
  for (int l = 0; l < 8; ++l) {
    int i4 = tid + l * 256;
    int row = i4 >> 5, c4 = i4 & 31;
    *(float4*)&Hs[row * 132 + 4 * c4] = *(const float4*)&hsrc[(size_t)i4 * 4];
  }
  const int tx = tid & 15, ty = tid >> 4;
  for (int pass = 0; pass < 4; ++pass) {
    const float* W; int wstride;
    if (pass == 0)      { W = Wq;      wstride = ND; }
    else if (pass == 1) { W = Wk;      wstride = ND; }
    else if (pass == 2) { W = Wf;      wstride = WFR; }
    else                { W = Wf + ND; wstride = WFR; }
    __syncthreads();
    #pragma unroll
    for (int l = 0; l < 16; ++l) {
      int i4 = tid + l * 256;
      int row = i4 >> 5, c4 = i4 & 31;
      *(float4*)&Ws[row * 132 + 4 * c4] = *(const float4*)&W[(size_t)row * wstride + 4 * c4];
    }
    __syncthreads();
    float acc[4][8];
    #pragma unroll
    for (int i = 0; i < 4; ++i)
      #pragma unroll
      for (int j = 0; j < 8; ++j) acc[i][j] = 0.f;
    for (int d = 0; d < ND; d += 4) {
      float4 a4[4], b4[8];
      #pragma unroll
      for (int i = 0; i < 4; ++i) a4[i] = *(const float4*)&Hs[(ty + 16 * i) * 132 + d];
      #pragma unroll
      for (int j = 0; j < 8; ++j) b4[j] = *(const float4*)&Ws[(tx + 16 * j) * 132 + d];
      #pragma unroll
      for (int i = 0; i < 4; ++i)
        #pragma unroll
        for (int j = 0; j < 8; ++j)
          acc[i][j] += a4[i].x * b4[j].x + a4[i].y * b4[j].y
                     + a4[i].z * b4[j].z + a4[i].w * b4[j].w;
    }
    float* dst = (pass == 0) ? qo : (pass == 1) ? ko : (pass == 2) ? Ao : BEo;
    #pragma unroll
    for (int j = 0; j < 8; ++j) {
      const int h = tx + 16 * j;
      float bias;
      if (pass == 0)      bias = bq[h];
      else if (pass == 1) bias = bk[h];
      else if (pass == 2) bias = bf[h];
      else                bias = Ej[(size_t)bn * ND + h];
      #pragma unroll
      for (int i = 0; i < 4; ++i) {
        const int t = ty + 16 * i;
        dst[(size_t)bn * NT * 128 + t * 128 + h] = acc[i][j] + bias;
      }
    }
  }
}

// ---------------- kernel C1: S[b,t,i,j] = (q_t . k_t^T) * SCALE
__global__ __launch_bounds__(256) void kC1(const float* __restrict__ qb,
                                           const float* __restrict__ kb,
                                           float* __restrict__ S) {
  __shared__ __align__(16) float qs[64 * 132];
  __shared__ __align__(16) float ks[128 * 132];
  const int bt = blockIdx.x;
  const int b = bt >> 6, t = bt & 63;
  const int i0 = blockIdx.y * 64;
  const int j0 = blockIdx.z * 128;
  const int tid = threadIdx.x;
  #pragma unroll
  for (int l = 0; l < 8; ++l) {
    int i4 = tid + l * 256;
    int row = i4 >> 5, c4 = i4 & 31;
    *(float4*)&qs[row * 132 + 4 * c4] =
        *(const float4*)&qb[((size_t)(b * NS + i0 + row) * NT + t) * NH + 4 * c4];
  }
  #pragma unroll
  for (int l = 0; l < 16; ++l) {
    int i4 = tid + l * 256;
    int row = i4 >> 5, c4 = i4 & 31;
    *(float4*)&ks[row * 132 + 4 * c4] =
        *(const float4*)&kb[((size_t)(b * NS + j0 + row) * NT + t) * NH + 4 * c4];
  }
  __syncthreads();
  const int tx = tid & 15, ty = tid >> 4;
  float acc[4][8];
  #pragma unroll
  for (int i = 0; i < 4; ++i)
    #pragma unroll
    for (int j = 0; j < 8; ++j) acc[i][j] = 0.f;
  for (int h = 0; h < NH; h += 4) {
    float4 a4[4], b4[8];
    #pragma unroll
    for (int i = 0; i < 4; ++i) a4[i] = *(const float4*)&qs[(ty + 16 * i) * 132 + h];
    #pragma unroll
    for (int j = 0; j < 8; ++j) b4[j] = *(const float4*)&ks[(tx + 16 * j) * 132 + h];
    #pragma unroll
    for (int i = 0; i < 4; ++i)
      #pragma unroll
      for (int j = 0; j < 8; ++j)
        acc[i][j] += a4[i].x * b4[j].x + a4[i].y * b4[j].y
                   + a4[i].z * b4[j].z + a4[i].w * b4[j].w;
  }
  #pragma unroll
  for (int i = 0; i < 4; ++i)
    #pragma unroll
    for (int j = 0; j < 8; ++j)
      S[((size_t)(b * NT + t) * NS + i0 + ty + 16 * i) * NS + j0 + tx + 16 * j] =
          acc[i][j] * SCALE;
}

// ---------------- kernel C2: per (b,i): scores += q.rproj, softmax_t, mask,
// wsum, w-writeback, and zacc = Apb*wsum + (w.R).W3^T  (reassociated Cij term)
__global__ __launch_bounds__(256) void kC2(
    const float* __restrict__ R, const float* __restrict__ Wr,
    const float* __restrict__ br, const float* __restrict__ Wf,
    const float* __restrict__ qb, const float* __restrict__ Apb,
    float* __restrict__ S, float* __restrict__ zacc) {
  __shared__ __align__(16) float Ssm[64 * 260];  // [t][j]
  __shared__ __align__(16) float qs[64 * 128];   // [t][h]
  __shared__ float Rs[256 * 33];                 // [j][r]
  __shared__ float GM[64 * 34];                  // G (q.Wr, +qbr col 32); later M (w.R); also wred
  __shared__ float Wrs[128 * 33];                // Wr[h][r] + br in col 32; later W3[e][r]
  __shared__ float wsums[64];
  const int bi = blockIdx.x;
  const int b = bi >> 8, i = bi & 255;
  const int tid = threadIdx.x;

  #pragma unroll 2
  for (int l = 0; l < 16; ++l) {
    int i4 = tid + l * 256;
    int t = i4 >> 6, c4 = i4 & 63;
    *(float4*)&Ssm[t * 260 + 4 * c4] =
        *(const float4*)&S[((size_t)(b * NT + t) * NS + i) * NS + 4 * c4];
  }
  #pragma unroll 2
  for (int l = 0; l < 8; ++l) {
    int i4 = tid + l * 256;
    int t = i4 >> 5, c4 = i4 & 31;
    *(float4*)&qs[t * 128 + 4 * c4] =
        *(const float4*)&qb[((size_t)(b * NS + i) * NT + t) * NH + 4 * c4];
  }
  {
    const float* Rsrc = R + (size_t)(b * NS + i) * NS * NR;
    #pragma unroll 2
    for (int l = 0; l < 32; ++l) {
      int idx = tid + l * 256;
      Rs[(idx >> 5) * 33 + (idx & 31)] = Rsrc[idx];
    }
  }
  #pragma unroll 2
  for (int l = 0; l < 16; ++l) {
    int idx = tid + l * 256;
    Wrs[(idx >> 5) * 33 + (idx & 31)] = Wr[idx];
  }
  if (tid < 128) Wrs[tid * 33 + 32] = br[tid];
  __syncthreads();

  // G[t][r] = sum_h q[t][h]*Wr[h][r]; G[t][32] = q.br
  {
    const int r = tid & 31, t8 = tid >> 5;
    #pragma unroll 1
    for (int l = 0; l < 8; ++l) {
      const int t = t8 * 8 + l;
      float g = 0.f;
      #pragma unroll 8
      for (int h = 0; h < NH; ++h) g += qs[t * 128 + h] * Wrs[h * 33 + r];
      GM[t * 34 + r] = g;
    }
    if (tid < 64) {
      float g = 0.f;
      #pragma unroll 8
      for (int h = 0; h < NH; ++h) g += qs[tid * 128 + h] * Wrs[h * 33 + 32];
      GM[tid * 34 + 32] = g;
    }
  }
  __syncthreads();

  // Ssm[t][j] += (G[t][:].R[j][:] + qbr[t]) * SCALE
  {
    const int txl = tid & 15, tyl = tid >> 4;
    for (int jc = 0; jc < 4; ++jc) {
      float p[4][4];
      #pragma unroll
      for (int a = 0; a < 4; ++a)
        #pragma unroll
        for (int c = 0; c < 4; ++c) p[a][c] = 0.f;
      #pragma unroll
      for (int r = 0; r < 32; ++r) {
        float av[4], bv[4];
        #pragma unroll
        for (int a = 0; a < 4; ++a) av[a] = GM[(txl + 16 * a) * 34 + r];
        #pragma unroll
        for (int c = 0; c < 4; ++c) bv[c] = Rs[(jc * 64 + tyl + 16 * c) * 33 + r];
        #pragma unroll
        for (int a = 0; a < 4; ++a)
          #pragma unroll
          for (int c = 0; c < 4; ++c) p[a][c] += av[a] * bv[c];
      }
      #pragma unroll
      for (int a = 0; a < 4; ++a) {
        const int t = txl + 16 * a;
        const float qbr = GM[t * 34 + 32];
        #pragma unroll
        for (int c = 0; c < 4; ++c) {
          const int j = jc * 64 + tyl + 16 * c;
          Ssm[t * 260 + j] += (p[a][c] + qbr) * SCALE;
        }
      }
    }
  }
  __syncthreads();

  // softmax over t per column j, then diagonal mask (zero column j==i)
  {
    const int j = tid;
    float mx = -1e30f;
    #pragma unroll 8
    for (int t = 0; t < NT; ++t) mx = fmaxf(mx, Ssm[t * 260 + j]);
    float sm = 0.f;
    #pragma unroll 8
    for (int t = 0; t < NT; ++t) {
      const float v = __expf(Ssm[t * 260 + j] - mx);
      Ssm[t * 260 + j] = v;
      sm += v;
    }
    float inv = 1.f / sm;
    if (j == i) inv = 0.f;
    #pragma unroll 8
    for (int t = 0; t < NT; ++t) Ssm[t * 260 + j] *= inv;
  }
  __syncthreads();

  // wsum[t] = sum_j w[t][j]
  {
    const int t = tid & 63, qtr = tid >> 6;
    float s = 0.f;
    #pragma unroll 8
    for (int jj = 0; jj < 64; ++jj) s += Ssm[t * 260 + qtr * 64 + jj];
    GM[tid] = s;  // G is dead; reuse as reduction scratch
    __syncthreads();
    if (tid < 64) wsums[tid] = GM[tid] + GM[tid + 64] + GM[tid + 128] + GM[tid + 192];
  }
  __syncthreads();

  // write w back to S; reload Wrs with W3
  #pragma unroll 2
  for (int l = 0; l < 16; ++l) {
    int i4 = tid + l * 256;
    int t = i4 >> 6, c4 = i4 & 63;
    *(float4*)&S[((size_t)(b * NT + t) * NS + i) * NS + 4 * c4] =
        *(const float4*)&Ssm[t * 260 + 4 * c4];
  }
  #pragma unroll 2
  for (int l = 0; l < 16; ++l) {
    int idx = tid + l * 256;
    Wrs[(idx >> 5) * 33 + (idx & 31)] = Wf[(size_t)(idx >> 5) * WFR + 2 * ND + (idx & 31)];
  }
  __syncthreads();

  // M[t][r] = sum_j w[t][j]*R[j][r]
  {
    const int r = tid & 31, t8 = tid >> 5;
    #pragma unroll 1
    for (int l = 0; l < 8; ++l) {
      const int t = t8 * 8 + l;
      float m = 0.f;
      #pragma unroll 8
      for (int j = 0; j < NS; ++j) m += Ssm[t * 260 + j] * Rs[j * 33 + r];
      GM[t * 34 + r] = m;
    }
  }
  __syncthreads();

  // T2[t][e] = sum_r M[t][r]*W3[e][r]; zacc = Apb*wsum + T2
  const int tx = tid & 15, ty = tid >> 4;
  float acc2[4][8];
  #pragma unroll
  for (int it = 0; it < 4; ++it)
    #pragma unroll
    for (int je = 0; je < 8; ++je) acc2[it][je] = 0.f;
  #pragma unroll
  for (int r = 0; r < 32; ++r) {
    float av[4], bv[8];
    #pragma unroll
    for (int it = 0; it < 4; ++it) av[it] = GM[(ty + 16 * it) * 34 + r];
    #pragma unroll
    for (int je = 0; je < 8; ++je) bv[je] = Wrs[(tx + 16 * je) * 33 + r];
    #pragma unroll
    for (int it = 0; it < 4; ++it)
      #pragma unroll
      for (int je = 0; je < 8; ++je) acc2[it][je] += av[it] * bv[je];
  }
  #pragma unroll
  for (int it = 0; it < 4; ++it) {
    const int t = ty + 16 * it;
    const float wv = wsums[t];
    #pragma unroll
    for (int je = 0; je < 8; ++je) {
      const int e = tx + 16 * je;
      zacc[((size_t)(b * NT + t) * NS + i) * ND + e] =
          Apb[((size_t)(b * NS + i) * NT + t) * ND + e] * wv + acc2[it][je];
    }
  }
}

// ---------------- kernel D: T13 = w_t . BE_t, + zacc + H, LayerNorm, store
__global__ __launch_bounds__(256) void kD(const float* __restrict__ S,
    const float* __restrict__ BE, const float* __restrict__ zacc,
    const float* __restrict__ H,
    const float* __restrict__ gamma, const float* __restrict__ beta,
    float* __restrict__ out) {
  __shared__ __align__(16) float wt[64 * 68];
  __shared__ __align__(16) float bes[64 * 132];
  const int bt = blockIdx.x;
  const int b = bt >> 6, t = bt & 63;
  const int i0 = blockIdx.y * 64;
  const int tid = threadIdx.x;
  const int tx = tid & 15, ty = tid >> 4;
  float acc[4][2][4];
  #pragma unroll
  for (int ii = 0; ii < 4; ++ii)
    #pragma unroll
    for (int je = 0; je < 2; ++je)
      #pragma unroll
      for (int c = 0; c < 4; ++c) acc[ii][je][c] = 0.f;
  for (int jc = 0; jc < 4; ++jc) {
    __syncthreads();
    #pragma unroll
    for (int l = 0; l < 4; ++l) {
      int i4 = tid + l * 256;
      int row = i4 >> 4, c4 = i4 & 15;
      *(float4*)&wt[row * 68 + 4 * c4] =
          *(const float4*)&S[((size_t)(b * NT + t) * NS + i0 + row) * NS + jc * 64 + 4 * c4];
    }
    #pragma unroll
    for (int l = 0; l < 8; ++l) {
      int i4 = tid + l * 256;
      int row = i4 >> 5, c4 = i4 & 31;
      *(float4*)&bes[row * 132 + 4 * c4] =
          *(const float4*)&BE[((size_t)(b * NS + jc * 64 + row) * NT + t) * ND + 4 * c4];
    }
    __syncthreads();
    for (int jl = 0; jl < 64; ++jl) {
      float a[4];
      #pragma unroll
      for (int ii = 0; ii < 4; ++ii) a[ii] = wt[(ty + 16 * ii) * 68 + jl];
      const float4 b0 = *(const float4*)&bes[jl * 132 + 4 * tx];
      const float4 b1 = *(const float4*)&bes[jl * 132 + 4 * tx + 64];
      #pragma unroll
      for (int ii = 0; ii < 4; ++ii) {
        acc[ii][0][0] += a[ii] * b0.x;
        acc[ii][0][1] += a[ii] * b0.y;
        acc[ii][0][2] += a[ii] * b0.z;
        acc[ii][0][3] += a[ii] * b0.w;
        acc[ii][1][0] += a[ii] * b1.x;
        acc[ii][1][1] += a[ii] * b1.y;
        acc[ii][1][2] += a[ii] * b1.z;
        acc[ii][1][3] += a[ii] * b1.w;
      }
    }
  }
  #pragma unroll
  for (int ii = 0; ii < 4; ++ii) {
    const int i = i0 + ty + 16 * ii;
    const size_t zoff = ((size_t)(b * NT + t) * NS + i) * ND;
    const size_t hoff = ((size_t)(b * NS + i) * NT + t) * ND;
    float x[2][4];
    float sum = 0.f, sq = 0.f;
    #pragma unroll
    for (int je = 0; je < 2; ++je) {
      const int e0 = 4 * tx + 64 * je;
      const float4 zv = *(const float4*)&zacc[zoff + e0];
      const float4 hv = *(const float4*)&H[hoff + e0];
      const float zz[4] = {zv.x, zv.y, zv.z, zv.w};
      const float hh[4] = {hv.x, hv.y, hv.z, hv.w};
      #pragma unroll
      for (int c = 0; c < 4; ++c) {
        const float v = acc[ii][je][c] + zz[c] + hh[c];
        x[je][c] = v;
        sum += v;
        sq += v * v;
      }
    }
    #pragma unroll
    for (int m = 1; m < 16; m <<= 1) {
      sum += __shfl_xor(sum, m, 64);
      sq  += __shfl_xor(sq, m, 64);
    }
    const float mu = sum * (1.f / 128.f);
    const float var = sq * (1.f / 128.f) - mu * mu;
    const float inv = rsqrtf(var + 1e-5f);
    #pragma unroll
    for (int je = 0; je < 2; ++je) {
      const int e0 = 4 * tx + 64 * je;
      const float4 gv = *(const float4*)&gamma[e0];
      const float4 bv = *(const float4*)&beta[e0];
      float4 o;
      o.x = (x[je][0] - mu) * inv * gv.x + bv.x;
      o.y = (x[je][1] - mu) * inv * gv.y + bv.y;
      o.z = (x[je][2] - mu) * inv * gv.z + bv.z;
      o.w = (x[je][3] - mu) * inv * gv.w + bv.w;
      *(float4*)&out[hoff + e0] = o;
    }
  }
}

extern "C" void kernel_launch(void* const* d_in, const int* in_sizes, int n_in,
                              void* d_out, int out_size, void* d_ws, size_t ws_size,
                              hipStream_t stream) {
  (void)in_sizes; (void)n_in; (void)out_size; (void)ws_size;
  const float* H     = (const float*)d_in[0];
  const float* R     = (const float*)d_in[1];
  const float* dH    = (const float*)d_in[2];
  const float* Wq    = (const float*)d_in[3];
  const float* bq    = (const float*)d_in[4];
  const float* Wk    = (const float*)d_in[5];
  const float* bk    = (const float*)d_in[6];
  const float* Wr    = (const float*)d_in[7];
  const float* br    = (const float*)d_in[8];
  const float* Wf    = (const float*)d_in[9];
  const float* bf    = (const float*)d_in[10];
  const float* gamma = (const float*)d_in[11];
  const float* beta  = (const float*)d_in[12];
  float* out = (float*)d_out;
  float* ws  = (float*)d_ws;

  // workspace layout (floats): total 50,528,256 fp32 = ~193 MiB
  float* qb    = ws + 0;         // 8,388,608  q[b][i][t][h]
  float* kb    = ws + 8388608;   // 8,388,608  k; reused as zacc[b][t][i][e] after kC1
  float* Apb   = ws + 16777216;  // 8,388,608  (A+bf)[b][i][t][e]
  float* BEb   = ws + 25165824;  // 8,388,608  (Bj+Ej)[b][j][t][e]
  float* Sb    = ws + 33554432;  // 16,777,216 scores/w [b][t][i][j]
  float* Ejb   = ws + 50331648;  //   131,072  Ej[b][j][e]

  kA<<<dim3(NB * NS), dim3(128), 0, stream>>>(dH, Wf, Ejb);
  kB<<<dim3(NB * NS), dim3(256), 0, stream>>>(H, Wq, bq, Wk, bk, Wf, bf, Ejb,
                                              qb, kb, Apb, BEb);
  kC1<<<dim3(NB * NT, 4, 2), dim3(256), 0, stream>>>(qb, kb, Sb);
  kC2<<<dim3(NB * NS), dim3(256), 0, stream>>>(R, Wr, br, Wf, qb, Apb, Sb, kb);
  kD<<<dim3(NB * NT, 4), dim3(256), 0, stream>>>(Sb, BEb, kb, H, gamma, beta, out);
}

// Round 2
// 179.764 us; speedup vs baseline: 3.7070x; 3.7070x over previous
//
#include <hip/hip_runtime.h>

typedef __attribute__((ext_vector_type(4))) float f32x4;
typedef __attribute__((ext_vector_type(8))) short short8;

constexpr int NB = 4, NS = 256, NT = 64, ND = 128, NR = 32;
constexpr int WFR = 3 * ND + NR;              // 416
constexpr float SCALE = 0.08838834764831845f; // 1/sqrt(128)

__device__ __forceinline__ unsigned short f2bf(float f) {
  unsigned x = __float_as_uint(f);
  return (unsigned short)((x + 0x7FFFu + ((x >> 16) & 1u)) >> 16);
}
__device__ __forceinline__ float bf2f(unsigned short u) {
  return __uint_as_float((unsigned)u << 16);
}

// ---------------- kP: weight prep (bf16 cvts + Wqrt = SCALE*Wq^T*[Wr|br])
__global__ __launch_bounds__(256) void kP(const float* __restrict__ Wq,
    const float* __restrict__ Wk, const float* __restrict__ Wr,
    const float* __restrict__ br, const float* __restrict__ bq,
    const float* __restrict__ Wf,
    unsigned short* __restrict__ Wqb, unsigned short* __restrict__ Wkb,
    unsigned short* __restrict__ W1b, unsigned short* __restrict__ W2b,
    unsigned short* __restrict__ W3b, unsigned short* __restrict__ Wqrt,
    float* __restrict__ Gbias) {
  const int blk = blockIdx.x, tid = threadIdx.x;
  if (blk < 64) {
    const int which = blk >> 4;
    const int idx = ((blk & 15) * 256 + tid) * 4;
    const int e = idx >> 7, d = idx & 127;
    float4 v;
    unsigned short* dst;
    if (which == 0)      { v = *(const float4*)&Wq[idx];            dst = Wqb; }
    else if (which == 1) { v = *(const float4*)&Wk[idx];            dst = Wkb; }
    else if (which == 2) { v = *(const float4*)&Wf[e * WFR + d];        dst = W1b; }
    else                 { v = *(const float4*)&Wf[e * WFR + ND + d];   dst = W2b; }
    dst[idx + 0] = f2bf(v.x); dst[idx + 1] = f2bf(v.y);
    dst[idx + 2] = f2bf(v.z); dst[idx + 3] = f2bf(v.w);
  } else if (blk < 68) {
    const int idx = ((blk - 64) * 256 + tid) * 4;
    const int e = idx >> 5, r = idx & 31;
    float4 v = *(const float4*)&Wf[e * WFR + 2 * ND + r];
    W3b[idx + 0] = f2bf(v.x); W3b[idx + 1] = f2bf(v.y);
    W3b[idx + 2] = f2bf(v.z); W3b[idx + 3] = f2bf(v.w);
  } else {
    const int rr = blk - 68;  // 0..47
    __shared__ float Vl[128];
    __shared__ float gbl[128];
    if (tid < 128) {
      float v = 0.f;
      if (rr < 32) v = Wr[tid * 32 + rr];
      else if (rr == 32) v = br[tid];
      Vl[tid] = v;
      gbl[tid] = bq[tid] * v;
    }
    __syncthreads();
    if (tid < 128) {
      float acc = 0.f;
      #pragma unroll 8
      for (int h = 0; h < 128; ++h) acc += Wq[h * 128 + tid] * Vl[h];
      Wqrt[rr * 128 + tid] = f2bf(acc * SCALE);
    }
    if (tid == 0) {
      float g = 0.f;
      for (int h = 0; h < 128; ++h) g += gbl[h];
      Gbias[rr] = g * SCALE;
    }
  }
}

// ---------------- kA: Ej[b,j,e] = (sum_t dH[b,j,t,:]) . W4[e,:]
__global__ __launch_bounds__(128) void kA(const float* __restrict__ dH,
                                          const float* __restrict__ Wf,
                                          float* __restrict__ Ej) {
  __shared__ float ds[ND];
  const int bj = blockIdx.x;
  const int d = threadIdx.x;
  const float* p = dH + (size_t)bj * NT * ND + d;
  float s = 0.f;
  #pragma unroll 8
  for (int t = 0; t < NT; ++t) s += p[t * ND];
  ds[d] = s;
  __syncthreads();
  const float* w4 = Wf + (size_t)d * WFR + 2 * ND + NR;
  float acc = 0.f;
  #pragma unroll 8
  for (int dd = 0; dd < ND; ++dd) acc += ds[dd] * w4[dd];
  Ej[(size_t)bj * ND + d] = acc;
}

// ---------------- kR: R f32 -> Rb bf16 (same [b][i][j][r] layout)
__global__ __launch_bounds__(256) void kR(const float* __restrict__ R,
                                          unsigned short* __restrict__ Rb) {
  const size_t idx = ((size_t)blockIdx.x * 256 + threadIdx.x) * 4;
  float4 v = *(const float4*)&R[idx];
  Rb[idx + 0] = f2bf(v.x); Rb[idx + 1] = f2bf(v.y);
  Rb[idx + 2] = f2bf(v.z); Rb[idx + 3] = f2bf(v.w);
}

__device__ __forceinline__ void gemm_tile(const short8 (&afr)[4][4],
    const unsigned short* __restrict__ Wp, int nt, int l15, int l4,
    f32x4 (&acc)[4]) {
  #pragma unroll
  for (int mt = 0; mt < 4; ++mt) acc[mt] = (f32x4){0.f, 0.f, 0.f, 0.f};
  #pragma unroll
  for (int kt = 0; kt < 4; ++kt) {
    short8 bfr = *(const short8*)(Wp + (16 * nt + l15) * 128 + 32 * kt + 8 * l4);
    #pragma unroll
    for (int mt = 0; mt < 4; ++mt)
      acc[mt] = __builtin_amdgcn_mfma_f32_16x16x32_bf16(afr[mt][kt], bfr, acc[mt], 0, 0, 0);
  }
}

// ---------------- kB: per (b,n): q,k (bf16), Apb=A+bf (f32), BE=B+Ej (bf16), G (bf16)
__global__ __launch_bounds__(256) void kB(const float* __restrict__ H,
    const unsigned short* __restrict__ Wqb, const unsigned short* __restrict__ Wkb,
    const unsigned short* __restrict__ W1b, const unsigned short* __restrict__ W2b,
    const unsigned short* __restrict__ Wqrt, const float* __restrict__ Gbias,
    const float* __restrict__ bq, const float* __restrict__ bk,
    const float* __restrict__ bf, const float* __restrict__ Ej,
    unsigned short* __restrict__ qb, unsigned short* __restrict__ kb,
    float* __restrict__ Apb, unsigned short* __restrict__ BEb,
    unsigned short* __restrict__ Gb) {
  const int bn = blockIdx.x, tid = threadIdx.x;
  const int lane = tid & 63, wv = tid >> 6;
  const int l15 = lane & 15, l4 = lane >> 4;
  // A-fragments of H (bf16 on the fly), resident for all passes
  short8 afr[4][4];
  const float* hb = H + (size_t)bn * (NT * ND);
  #pragma unroll
  for (int mt = 0; mt < 4; ++mt)
    #pragma unroll
    for (int kt = 0; kt < 4; ++kt) {
      const float* p = hb + (16 * mt + l15) * ND + 32 * kt + 8 * l4;
      float4 u0 = *(const float4*)p;
      float4 u1 = *(const float4*)(p + 4);
      short8 f;
      f[0] = (short)f2bf(u0.x); f[1] = (short)f2bf(u0.y);
      f[2] = (short)f2bf(u0.z); f[3] = (short)f2bf(u0.w);
      f[4] = (short)f2bf(u1.x); f[5] = (short)f2bf(u1.y);
      f[6] = (short)f2bf(u1.z); f[7] = (short)f2bf(u1.w);
      afr[mt][kt] = f;
    }
  f32x4 acc[4];
  // pass 0: q
  #pragma unroll
  for (int n2 = 0; n2 < 2; ++n2) {
    const int nt = 2 * wv + n2, c = 16 * nt + l15;
    gemm_tile(afr, Wqb, nt, l15, l4, acc);
    const float bias = bq[c];
    #pragma unroll
    for (int mt = 0; mt < 4; ++mt)
      #pragma unroll
      for (int jr = 0; jr < 4; ++jr) {
        const int tr = 16 * mt + 4 * l4 + jr;
        qb[(size_t)bn * 8192 + tr * 128 + c] = f2bf(acc[mt][jr] + bias);
      }
  }
  // pass 1: k
  #pragma unroll
  for (int n2 = 0; n2 < 2; ++n2) {
    const int nt = 2 * wv + n2, c = 16 * nt + l15;
    gemm_tile(afr, Wkb, nt, l15, l4, acc);
    const float bias = bk[c];
    #pragma unroll
    for (int mt = 0; mt < 4; ++mt)
      #pragma unroll
      for (int jr = 0; jr < 4; ++jr) {
        const int tr = 16 * mt + 4 * l4 + jr;
        kb[(size_t)bn * 8192 + tr * 128 + c] = f2bf(acc[mt][jr] + bias);
      }
  }
  // pass 2: Apb = H.W1 + bf  (f32)
  #pragma unroll
  for (int n2 = 0; n2 < 2; ++n2) {
    const int nt = 2 * wv + n2, c = 16 * nt + l15;
    gemm_tile(afr, W1b, nt, l15, l4, acc);
    const float bias = bf[c];
    #pragma unroll
    for (int mt = 0; mt < 4; ++mt)
      #pragma unroll
      for (int jr = 0; jr < 4; ++jr) {
        const int tr = 16 * mt + 4 * l4 + jr;
        Apb[(size_t)bn * 8192 + tr * 128 + c] = acc[mt][jr] + bias;
      }
  }
  // pass 3: BE = H.W2 + Ej  (bf16)
  #pragma unroll
  for (int n2 = 0; n2 < 2; ++n2) {
    const int nt = 2 * wv + n2, c = 16 * nt + l15;
    gemm_tile(afr, W2b, nt, l15, l4, acc);
    const float bias = Ej[(size_t)bn * 128 + c];
    #pragma unroll
    for (int mt = 0; mt < 4; ++mt)
      #pragma unroll
      for (int jr = 0; jr < 4; ++jr) {
        const int tr = 16 * mt + 4 * l4 + jr;
        BEb[(size_t)bn * 8192 + tr * 128 + c] = f2bf(acc[mt][jr] + bias);
      }
  }
  // pass 4: G = H.Wqrt + Gbias (bf16, 48 cols; col32 = qbr)
  if (wv < 3) {
    const int nt = wv, c = 16 * nt + l15;
    gemm_tile(afr, Wqrt, nt, l15, l4, acc);
    const float bias = Gbias[c];
    #pragma unroll
    for (int mt = 0; mt < 4; ++mt)
      #pragma unroll
      for (int jr = 0; jr < 4; ++jr) {
        const int tr = 16 * mt + 4 * l4 + jr;
        Gb[(size_t)bn * 3072 + tr * 48 + c] = f2bf(acc[mt][jr] + bias);
      }
  }
}

// ---------------- kC1: S[b,i,t,j] = SCALE * q_t . k_t^T  (bf16 out)
__global__ __launch_bounds__(256) void kC1(const unsigned short* __restrict__ qb,
    const unsigned short* __restrict__ kb, unsigned short* __restrict__ Sb) {
  const int bt = blockIdx.x, jq = blockIdx.y;
  const int b = bt >> 6, t = bt & 63;
  const int tid = threadIdx.x, lane = tid & 63, wv = tid >> 6;
  const int l15 = lane & 15, l4 = lane >> 4;
  f32x4 acc[4][4];
  #pragma unroll
  for (int mi = 0; mi < 4; ++mi)
    #pragma unroll
    for (int nt = 0; nt < 4; ++nt) acc[mi][nt] = (f32x4){0.f, 0.f, 0.f, 0.f};
  #pragma unroll
  for (int kt = 0; kt < 4; ++kt) {
    short8 a[4], bb[4];
    #pragma unroll
    for (int mi = 0; mi < 4; ++mi) {
      const int i = 64 * wv + 16 * mi + l15;
      a[mi] = *(const short8*)(qb + ((size_t)(b * 256 + i) * 64 + t) * 128 + 32 * kt + 8 * l4);
    }
    #pragma unroll
    for (int nt = 0; nt < 4; ++nt) {
      const int j = 64 * jq + 16 * nt + l15;
      bb[nt] = *(const short8*)(kb + ((size_t)(b * 256 + j) * 64 + t) * 128 + 32 * kt + 8 * l4);
    }
    #pragma unroll
    for (int mi = 0; mi < 4; ++mi)
      #pragma unroll
      for (int nt = 0; nt < 4; ++nt)
        acc[mi][nt] = __builtin_amdgcn_mfma_f32_16x16x32_bf16(a[mi], bb[nt], acc[mi][nt], 0, 0, 0);
  }
  #pragma unroll
  for (int mi = 0; mi < 4; ++mi)
    #pragma unroll
    for (int nt = 0; nt < 4; ++nt)
      #pragma unroll
      for (int jr = 0; jr < 4; ++jr) {
        const int i = 64 * wv + 16 * mi + 4 * l4 + jr;
        const int j = 64 * jq + 16 * nt + l15;
        Sb[((size_t)(b * 256 + i) * 64 + t) * 256 + j] = f2bf(acc[mi][nt][jr] * SCALE);
      }
}

// ---------------- kSM: per (b,i): S += G.R^T + qbr, softmax_t, mask, wsum, w->bf16
__global__ __launch_bounds__(256) void kSM(const unsigned short* __restrict__ Gb,
    const unsigned short* __restrict__ Rb, const unsigned short* __restrict__ Sb,
    unsigned short* __restrict__ Wb, float* __restrict__ wsums) {
  __shared__ float wred[4][64];
  const int bi = blockIdx.x;
  const int b = bi >> 8, i = bi & 255;
  const int tid = threadIdx.x, lane = tid & 63, wv = tid >> 6;
  const int l15 = lane & 15, l4 = lane >> 4;
  // P = G . R^T  (K=32, one k-step)
  short8 ga[4];
  #pragma unroll
  for (int mt = 0; mt < 4; ++mt)
    ga[mt] = *(const short8*)(Gb + ((size_t)bi * 64 + 16 * mt + l15) * 48 + 8 * l4);
  f32x4 acc[4][4];
  const f32x4 zz = (f32x4){0.f, 0.f, 0.f, 0.f};
  #pragma unroll
  for (int nt = 0; nt < 4; ++nt) {
    const int j = 64 * wv + 16 * nt + l15;
    short8 rb = *(const short8*)(Rb + ((size_t)bi * 256 + j) * 32 + 8 * l4);
    #pragma unroll
    for (int mt = 0; mt < 4; ++mt)
      acc[mt][nt] = __builtin_amdgcn_mfma_f32_16x16x32_bf16(ga[mt], rb, zz, 0, 0, 0);
  }
  // + S + qbr
  float qbr[4][4];
  #pragma unroll
  for (int mt = 0; mt < 4; ++mt)
    #pragma unroll
    for (int jr = 0; jr < 4; ++jr) {
      const int t = 16 * mt + 4 * l4 + jr;
      qbr[mt][jr] = bf2f(Gb[((size_t)bi * 64 + t) * 48 + 32]);
    }
  #pragma unroll
  for (int mt = 0; mt < 4; ++mt)
    #pragma unroll
    for (int nt = 0; nt < 4; ++nt)
      #pragma unroll
      for (int jr = 0; jr < 4; ++jr) {
        const int t = 16 * mt + 4 * l4 + jr;
        const int j = 64 * wv + 16 * nt + l15;
        acc[mt][nt][jr] += bf2f(Sb[((size_t)bi * 64 + t) * 256 + j]) + qbr[mt][jr];
      }
  // softmax over t per column j (column = (wv,nt,l15); 16 vals/lane x 4 lanes)
  #pragma unroll
  for (int nt = 0; nt < 4; ++nt) {
    float mx = -1e30f;
    #pragma unroll
    for (int mt = 0; mt < 4; ++mt)
      #pragma unroll
      for (int jr = 0; jr < 4; ++jr) mx = fmaxf(mx, acc[mt][nt][jr]);
    mx = fmaxf(mx, __shfl_xor(mx, 16));
    mx = fmaxf(mx, __shfl_xor(mx, 32));
    float sm = 0.f;
    #pragma unroll
    for (int mt = 0; mt < 4; ++mt)
      #pragma unroll
      for (int jr = 0; jr < 4; ++jr) {
        const float e = __expf(acc[mt][nt][jr] - mx);
        acc[mt][nt][jr] = e;
        sm += e;
      }
    sm += __shfl_xor(sm, 16);
    sm += __shfl_xor(sm, 32);
    const int j = 64 * wv + 16 * nt + l15;
    const float inv = (j == i) ? 0.f : 1.f / sm;
    #pragma unroll
    for (int mt = 0; mt < 4; ++mt)
      #pragma unroll
      for (int jr = 0; jr < 4; ++jr) acc[mt][nt][jr] *= inv;
  }
  // wsum[t] = sum_j w[t][j]
  float part[4][4];
  #pragma unroll
  for (int mt = 0; mt < 4; ++mt)
    #pragma unroll
    for (int jr = 0; jr < 4; ++jr) {
      float s = 0.f;
      #pragma unroll
      for (int nt = 0; nt < 4; ++nt) s += acc[mt][nt][jr];
      part[mt][jr] = s;
    }
  #pragma unroll
  for (int m = 1; m < 16; m <<= 1)
    #pragma unroll
    for (int mt = 0; mt < 4; ++mt)
      #pragma unroll
      for (int jr = 0; jr < 4; ++jr) part[mt][jr] += __shfl_xor(part[mt][jr], m);
  if (l15 == 0) {
    #pragma unroll
    for (int mt = 0; mt < 4; ++mt)
      #pragma unroll
      for (int jr = 0; jr < 4; ++jr) wred[wv][16 * mt + 4 * l4 + jr] = part[mt][jr];
  }
  __syncthreads();
  if (tid < 64)
    wsums[(size_t)bi * 64 + tid] = wred[0][tid] + wred[1][tid] + wred[2][tid] + wred[3][tid];
  // store w bf16 -> Wb[b][t][i][j]
  #pragma unroll
  for (int mt = 0; mt < 4; ++mt)
    #pragma unroll
    for (int nt = 0; nt < 4; ++nt)
      #pragma unroll
      for (int jr = 0; jr < 4; ++jr) {
        const int t = 16 * mt + 4 * l4 + jr;
        const int j = 64 * wv + 16 * nt + l15;
        Wb[((size_t)(b * 64 + t) * 256 + i) * 256 + j] = f2bf(acc[mt][nt][jr]);
      }
}

// ---------------- kM: per (b,i) [one wave]: M = w.R; T2 = M.W3^T; zacc = Apb*wsum + T2 (in-place)
__global__ __launch_bounds__(256) void kM(const unsigned short* __restrict__ Wb,
    const unsigned short* __restrict__ Rb, const unsigned short* __restrict__ W3b,
    const float* __restrict__ wsums, float* __restrict__ Apb) {
  __shared__ unsigned short Ml[4][64 * 40];
  const int tid = threadIdx.x, lane = tid & 63, wv = tid >> 6;
  const int bi = blockIdx.x * 4 + wv;
  const int b = bi >> 8, i = bi & 255;
  const int l15 = lane & 15, l4 = lane >> 4;
  f32x4 mac[4][2];
  #pragma unroll
  for (int mt = 0; mt < 4; ++mt)
    #pragma unroll
    for (int nt = 0; nt < 2; ++nt) mac[mt][nt] = (f32x4){0.f, 0.f, 0.f, 0.f};
  #pragma unroll
  for (int kt = 0; kt < 8; ++kt) {
    short8 a[4];
    #pragma unroll
    for (int mt = 0; mt < 4; ++mt) {
      const int t = 16 * mt + l15;
      a[mt] = *(const short8*)(Wb + ((size_t)(b * 64 + t) * 256 + i) * 256 + 32 * kt + 8 * l4);
    }
    short8 bb[2];
    #pragma unroll
    for (int nt = 0; nt < 2; ++nt) {
      const int r = 16 * nt + l15;
      short8 f;
      #pragma unroll
      for (int v = 0; v < 8; ++v) {
        const int j = 32 * kt + 8 * l4 + v;
        f[v] = (short)Rb[((size_t)bi * 256 + j) * 32 + r];
      }
      bb[nt] = f;
    }
    #pragma unroll
    for (int mt = 0; mt < 4; ++mt)
      #pragma unroll
      for (int nt = 0; nt < 2; ++nt)
        mac[mt][nt] = __builtin_amdgcn_mfma_f32_16x16x32_bf16(a[mt], bb[nt], mac[mt][nt], 0, 0, 0);
  }
  // repack M into LDS (bf16, [64][40] per wave)
  unsigned short* ml = Ml[wv];
  #pragma unroll
  for (int mt = 0; mt < 4; ++mt)
    #pragma unroll
    for (int nt = 0; nt < 2; ++nt)
      #pragma unroll
      for (int jr = 0; jr < 4; ++jr) {
        const int t = 16 * mt + 4 * l4 + jr;
        const int r = 16 * nt + l15;
        ml[t * 40 + r] = f2bf(mac[mt][nt][jr]);
      }
  // T2 = M . W3^T  (K=32)
  f32x4 tac[4][8];
  #pragma unroll
  for (int mt = 0; mt < 4; ++mt)
    #pragma unroll
    for (int nt = 0; nt < 8; ++nt) tac[mt][nt] = (f32x4){0.f, 0.f, 0.f, 0.f};
  short8 a2[4];
  #pragma unroll
  for (int mt = 0; mt < 4; ++mt)
    a2[mt] = *(const short8*)(ml + (16 * mt + l15) * 40 + 8 * l4);
  #pragma unroll
  for (int nt = 0; nt < 8; ++nt) {
    short8 w3 = *(const short8*)(W3b + (16 * nt + l15) * 32 + 8 * l4);
    #pragma unroll
    for (int mt = 0; mt < 4; ++mt)
      tac[mt][nt] = __builtin_amdgcn_mfma_f32_16x16x32_bf16(a2[mt], w3, tac[mt][nt], 0, 0, 0);
  }
  // epilogue: Apb <- Apb*wsum + T2
  #pragma unroll
  for (int mt = 0; mt < 4; ++mt)
    #pragma unroll
    for (int jr = 0; jr < 4; ++jr) {
      const int t = 16 * mt + 4 * l4 + jr;
      const float ws = wsums[(size_t)bi * 64 + t];
      #pragma unroll
      for (int nt = 0; nt < 8; ++nt) {
        const int e = 16 * nt + l15;
        const size_t off = ((size_t)bi * 64 + t) * 128 + e;
        Apb[off] = Apb[off] * ws + tac[mt][nt][jr];
      }
    }
}

// ---------------- kD: per (b,t): out = LN(H + zacc + w.BE)
__global__ __launch_bounds__(512) void kD(const unsigned short* __restrict__ Wb,
    const unsigned short* __restrict__ BEb, const float* __restrict__ zacc,
    const float* __restrict__ H, const float* __restrict__ gamma,
    const float* __restrict__ beta, float* __restrict__ out) {
  __shared__ unsigned short Bl[128 * 264];
  const int bt = blockIdx.x;
  const int b = bt >> 6, t = bt & 63;
  const int tid = threadIdx.x, lane = tid & 63, wv = tid >> 6;
  const int l15 = lane & 15, l4 = lane >> 4;
  // stage BE[j][e] -> Bl[e][j]  (transposed, pad 264)
  {
    const int j = tid >> 1, eh = (tid & 1) * 64;
    const unsigned short* src = BEb + ((size_t)(b * 256 + j) * 64 + t) * 128 + eh;
    #pragma unroll
    for (int eg = 0; eg < 8; ++eg) {
      short8 v = *(const short8*)(src + 8 * eg);
      #pragma unroll
      for (int u = 0; u < 8; ++u)
        Bl[(eh + 8 * eg + u) * 264 + j] = (unsigned short)v[u];
    }
  }
  __syncthreads();
  f32x4 acc[2][8];
  #pragma unroll
  for (int m2 = 0; m2 < 2; ++m2)
    #pragma unroll
    for (int nt = 0; nt < 8; ++nt) acc[m2][nt] = (f32x4){0.f, 0.f, 0.f, 0.f};
  #pragma unroll
  for (int kt = 0; kt < 8; ++kt) {
    short8 a[2];
    #pragma unroll
    for (int m2 = 0; m2 < 2; ++m2) {
      const int i = 32 * wv + 16 * m2 + l15;
      a[m2] = *(const short8*)(Wb + ((size_t)(b * 64 + t) * 256 + i) * 256 + 32 * kt + 8 * l4);
    }
    #pragma unroll
    for (int nt = 0; nt < 8; ++nt) {
      short8 bb = *(const short8*)(&Bl[(16 * nt + l15) * 264 + 32 * kt + 8 * l4]);
      #pragma unroll
      for (int m2 = 0; m2 < 2; ++m2)
        acc[m2][nt] = __builtin_amdgcn_mfma_f32_16x16x32_bf16(a[m2], bb, acc[m2][nt], 0, 0, 0);
    }
  }
  // epilogue: + zacc + H, LayerNorm over e, store
  float gam[8], bet[8];
  #pragma unroll
  for (int nt = 0; nt < 8; ++nt) {
    const int e = 16 * nt + l15;
    gam[nt] = gamma[e];
    bet[nt] = beta[e];
  }
  #pragma unroll
  for (int m2 = 0; m2 < 2; ++m2)
    #pragma unroll
    for (int jr = 0; jr < 4; ++jr) {
      const int i = 32 * wv + 16 * m2 + 4 * l4 + jr;
      const size_t base = ((size_t)(b * 256 + i) * 64 + t) * 128;
      float x[8];
      float sm = 0.f, sq = 0.f;
      #pragma unroll
      for (int nt = 0; nt < 8; ++nt) {
        const int e = 16 * nt + l15;
        const float v = acc[m2][nt][jr] + zacc[base + e] + H[base + e];
        x[nt] = v;
        sm += v;
        sq += v * v;
      }
      #pragma unroll
      for (int m = 1; m < 16; m <<= 1) {
        sm += __shfl_xor(sm, m);
        sq += __shfl_xor(sq, m);
      }
      const float mu = sm * (1.f / 128.f);
      const float inv = rsqrtf(sq * (1.f / 128.f) - mu * mu + 1e-5f);
      #pragma unroll
      for (int nt = 0; nt < 8; ++nt)
        out[base + 16 * nt + l15] = (x[nt] - mu) * inv * gam[nt] + bet[nt];
    }
}

extern "C" void kernel_launch(void* const* d_in, const int* in_sizes, int n_in,
                              void* d_out, int out_size, void* d_ws, size_t ws_size,
                              hipStream_t stream) {
  (void)in_sizes; (void)n_in; (void)out_size; (void)ws_size;
  const float* H     = (const float*)d_in[0];
  const float* R     = (const float*)d_in[1];
  const float* dH    = (const float*)d_in[2];
  const float* Wq    = (const float*)d_in[3];
  const float* bq    = (const float*)d_in[4];
  const float* Wk    = (const float*)d_in[5];
  const float* bk    = (const float*)d_in[6];
  const float* Wr    = (const float*)d_in[7];
  const float* br    = (const float*)d_in[8];
  const float* Wf    = (const float*)d_in[9];
  const float* bf    = (const float*)d_in[10];
  const float* gamma = (const float*)d_in[11];
  const float* beta  = (const float*)d_in[12];
  float* out = (float*)d_out;
  char* w = (char*)d_ws;

  unsigned short* qb  = (unsigned short*)(w + 0);          // 16,777,216
  unsigned short* kb  = (unsigned short*)(w + 16777216);   // 16,777,216
  unsigned short* Sb  = (unsigned short*)(w + 33554432);   // 33,554,432
  unsigned short* Wbw = (unsigned short*)(w + 67108864);   // 33,554,432
  float*          Apb = (float*)(w + 100663296);           // 33,554,432 (becomes zacc)
  unsigned short* BEb = (unsigned short*)(w + 134217728);  // 16,777,216
  unsigned short* Gb  = (unsigned short*)(w + 150994944);  //  6,291,456
  unsigned short* Rb  = (unsigned short*)(w + 157286400);  // 16,777,216
  float*          Ejb = (float*)(w + 174063616);           //    524,288
  float*          wsm = (float*)(w + 174587904);           //    262,144
  unsigned short* Wqb = (unsigned short*)(w + 174850048);  //     32,768
  unsigned short* Wkb = (unsigned short*)(w + 174882816);
  unsigned short* W1b = (unsigned short*)(w + 174915584);
  unsigned short* W2b = (unsigned short*)(w + 174948352);
  unsigned short* W3b = (unsigned short*)(w + 174981120);  //      8,192
  unsigned short* Wqrt= (unsigned short*)(w + 174989312);  //     12,288
  float*          Gbs = (float*)(w + 175001600);           //        192

  kP<<<dim3(116), dim3(256), 0, stream>>>(Wq, Wk, Wr, br, bq, Wf,
                                          Wqb, Wkb, W1b, W2b, W3b, Wqrt, Gbs);
  kA<<<dim3(NB * NS), dim3(128), 0, stream>>>(dH, Wf, Ejb);
  kR<<<dim3(8192), dim3(256), 0, stream>>>(R, Rb);
  kB<<<dim3(NB * NS), dim3(256), 0, stream>>>(H, Wqb, Wkb, W1b, W2b, Wqrt, Gbs,
                                              bq, bk, bf, Ejb, qb, kb, Apb, BEb, Gb);
  kC1<<<dim3(NB * NT, 4), dim3(256), 0, stream>>>(qb, kb, Sb);
  kSM<<<dim3(NB * NS), dim3(256), 0, stream>>>(Gb, Rb, Sb, Wbw, wsm);
  kM<<<dim3(NB * NS / 4), dim3(256), 0, stream>>>(Wbw, Rb, W3b, wsm, Apb);
  kD<<<dim3(NB * NT), dim3(512), 0, stream>>>(Wbw, BEb, Apb, H, gamma, beta, out);
}